// Round 3
// baseline (630.179 us; speedup 1.0000x reference)
//
#include <hip/hip_runtime.h>

#define N_NODES  50000
#define R_REL    3
#define E_EDGES  50000
#define EP_EDGES 100000
#define ELL_CAP  32

typedef __attribute__((ext_vector_type(8))) short  short8;
typedef __attribute__((ext_vector_type(8))) unsigned short ushort8;
typedef __attribute__((ext_vector_type(4))) float  floatx4;

static inline int cdiv_h(int a, int b) { return (a + b - 1) / b; }

__device__ inline unsigned short f2b(float f) {
    union { float f; unsigned u; } v; v.f = f;
    return (unsigned short)((v.u + 0x7FFF + ((v.u >> 16) & 1)) >> 16);
}
__device__ inline float b2f(unsigned short h) {
    union { unsigned u; float f; } v; v.u = ((unsigned)h) << 16;
    return v.f;
}

#define GLDS16(gp, lp) __builtin_amdgcn_global_load_lds( \
    (const __attribute__((address_space(1))) void*)(gp), \
    (__attribute__((address_space(3))) void*)(lp), 16, 0, 0)

// ---------------- degree count + ELL fill ----------------
__global__ void count_fill_kernel(const int* __restrict__ src, const int* __restrict__ dst,
                                  int* __restrict__ outcnt, int* __restrict__ incnt,
                                  int* __restrict__ ell) {
    int i = blockIdx.x * blockDim.x + threadIdx.x;
    if (i >= R_REL * E_EDGES) return;
    int r = i / E_EDGES;
    int s = src[i], d = dst[i];
    atomicAdd(&outcnt[r * N_NODES + s], 1);
    int k = atomicAdd(&incnt[r * N_NODES + d], 1);
    if (k < ELL_CAP)
        ell[((size_t)(r * N_NODES + d) << 5) + k] = s;
}

__global__ void norm_kernel(const int* __restrict__ cnt, float* __restrict__ nrm, int n) {
    int i = blockIdx.x * blockDim.x + threadIdx.x;
    if (i < n) nrm[i] = rsqrtf(fmaxf((float)cnt[i], 1.0f));
}

// ---------------- fp32 -> bf16 (8 elems/thread) ----------------
__global__ void f2b8_kernel(const float* __restrict__ in, unsigned short* __restrict__ out,
                            int total8) {
    int i = blockIdx.x * blockDim.x + threadIdx.x;
    if (i >= total8) return;
    float4 a = ((const float4*)in)[2 * i];
    float4 b = ((const float4*)in)[2 * i + 1];
    ushort8 o;
    o[0] = f2b(a.x); o[1] = f2b(a.y); o[2] = f2b(a.z); o[3] = f2b(a.w);
    o[4] = f2b(b.x); o[5] = f2b(b.y); o[6] = f2b(b.z); o[7] = f2b(b.w);
    ((ushort8*)out)[i] = o;
}

// ---------------- all weight transposes (4 layers + Wp1) in one launch ----------------
__global__ void prep_weights_kernel(
        const float* __restrict__ W0, const float* __restrict__ W1,
        const float* __restrict__ W2, const float* __restrict__ W3,
        const float* __restrict__ Wp1,
        unsigned short* __restrict__ Wt0, unsigned short* __restrict__ Wt1,
        unsigned short* __restrict__ Wt2, unsigned short* __restrict__ Wt3,
        unsigned short* __restrict__ But) {
    int i = blockIdx.x * blockDim.x + threadIdx.x;
    if (i < 786432) {                       // L0: K=512 dout=512 rows=1536 (no pad)
        int k = i & 511, nall = i >> 9, r = nall >> 9, n = nall & 511;
        Wt0[i] = f2b(W0[(((size_t)r << 9) + k) * 512 + n]);
    } else if (i < 1179648) {               // L1: K=512 dout=256 rows=768
        int j = i - 786432;
        int k = j & 511, nall = j >> 9, r = nall >> 8, n = nall & 255;
        Wt1[j] = f2b(W1[(((size_t)r << 9) + k) * 256 + n]);
    } else if (i < 1277952) {               // L2: K=256 dout=128 rows=384
        int j = i - 1179648;
        int k = j & 255, nall = j >> 8, r = nall >> 7, n = nall & 127;
        Wt2[j] = f2b(W2[(((size_t)r << 8) + k) * 128 + n]);
    } else if (i < 1310720) {               // L3: K=128 dout=64 rows=256 (pad 192..255)
        int j = i - 1277952;
        int k = j & 127, nall = j >> 7, r = nall >> 6, n = nall & 63;
        Wt3[j] = (r < R_REL) ? f2b(W3[(((size_t)r << 7) + k) * 64 + n]) : (unsigned short)0;
    } else if (i < 1318912) {               // Wp1 -> But[128][64]
        int j = i - 1310720;
        int k = j & 63, jo = j >> 6, jj = jo & 63, half = jo >> 6;
        But[j] = f2b(Wp1[(size_t)(half * 64 + k) * 64 + jj]);
    }
}

// ---------------- pipelined MFMA GEMM: C[m][n] = (A[m][:].Bt[n][:]) * sn[n/dout][m] -----
// BM=256 BN=128 BK=64, 512 thr = 8 waves (4M x 2N), per-wave 64x64 = 4x4 16x16 tiles.
// Triple-buffered LDS (144 KB) -> counted s_waitcnt vmcnt(6): tile t+1's 6 loads stay
// in flight across the barrier (T4), never a vmcnt(0) drain in the main loop.
// EXACTLY ONE s_barrier per K-tile (lesson from round 1: intra-tile barriers at
// 2 waves/SIMD lockstep-serialize the pipe; MfmaUtil 29->22%). The whole tile body
// {6x global_load_lds for t+2, 16x ds_read_b128, 32x MFMA} is one scheduling region;
// the compiler's fine-grained lgkmcnt scheduling (m97-verified) handles the rest.
// setprio(1) around each MFMA cluster: post-barrier waves diverge into load/MFMA
// roles, the regime where setprio pays. sched_barrier(0) after the s_barrier pins
// staging issues inside their own iteration (WAR safety for buffer (t+2)%3, which
// was last read before this barrier; those ds_reads completed pre-barrier because
// their results were consumed by that iteration's MFMAs).
// 8-chunk XOR swizzle kept (0 bank conflicts). K%64==0, NdPad%128==0.
// sn==nullptr -> scale 1, no rel guard.
// XCD-locality swizzle: blocks p==j (mod 8) share one m-panel across n-blocks.
__global__ __launch_bounds__(512, 2) void gemm_bf16_fused(
        const unsigned short* __restrict__ A, const unsigned short* __restrict__ Bt,
        unsigned short* __restrict__ C, const float* __restrict__ sn,
        int M, int K, int NdPad, int dout) {
    __shared__ unsigned short As[3 * 16384];   // 3 x [256][64]  (96 KB)
    __shared__ unsigned short Bs[3 * 8192];    // 3 x [128][64]  (48 KB)

    const int nN = gridDim.x, nM = gridDim.y;
    int p = blockIdx.y * nN + blockIdx.x;
    const int nig = nN << 3;
    int group = p / nig;
    int rem = p - group * nig;
    int gs = nM - (group << 3); if (gs > 8) gs = 8;
    int mb = (group << 3) + rem % gs;
    int nb = rem / gs;
    const int m0 = mb * 256, n0 = nb * 128;

    const int tid  = threadIdx.x;
    const int w    = tid >> 6;         // 0..7
    const int lane = tid & 63;
    const int wm   = w >> 1;           // 0..3 : 64-row quarter
    const int wn   = w & 1;            // 0..1 : 64-col half
    const int lrow8 = lane >> 3;       // 0..7 staging row within 8-row chunk
    const int cs    = ((lane & 7) ^ lrow8) << 3;  // swizzled src chunk offset (ushorts)

    floatx4 acc[4][4];
#pragma unroll
    for (int i = 0; i < 4; ++i)
#pragma unroll
        for (int j = 0; j < 4; ++j) acc[i][j] = (floatx4){0.f, 0.f, 0.f, 0.f};

    const int mrow  = lane & 15;
    const int phys0 = ((lane >> 4) ^ (lane & 7)) << 3;   // h=0 read offset (ushorts)
    const int phys1 = phys0 ^ 32;                        // h=1 (chunk c^4)
    const int NT = K >> 6;

#define STAGE_A(t, i) GLDS16(A + (size_t)(m0 + (i)*64 + 8*w + lrow8) * K + ((t) << 6) + cs, \
                             As + ((t) % 3) * 16384 + ((i)*64 + 8*w) * 64)
#define STAGE_B(t, i) GLDS16(Bt + (size_t)(n0 + (i)*64 + 8*w + lrow8) * K + ((t) << 6) + cs, \
                             Bs + ((t) % 3) * 8192 + ((i)*64 + 8*w) * 64)

    // prologue: stage tiles 0 and 1 (6 loads each per thread)
    STAGE_A(0, 0); STAGE_A(0, 1); STAGE_A(0, 2); STAGE_A(0, 3);
    STAGE_B(0, 0); STAGE_B(0, 1);
    if (NT > 1) {
        STAGE_A(1, 0); STAGE_A(1, 1); STAGE_A(1, 2); STAGE_A(1, 3);
        STAGE_B(1, 0); STAGE_B(1, 1);
    }

    for (int t = 0; t < NT; ++t) {
        const unsigned short* as = As + (t % 3) * 16384;
        const unsigned short* bs = Bs + (t % 3) * 8192;
        // counted wait: everything older than tile t+1's 6 loads has landed
        if (t + 1 < NT) asm volatile("s_waitcnt vmcnt(6)" ::: "memory");
        else            asm volatile("s_waitcnt vmcnt(0)" ::: "memory");
        __builtin_amdgcn_s_barrier();
        __builtin_amdgcn_sched_barrier(0);

        // stage tile t+2 (one whole-tile scheduling region; no more barriers)
        if (t + 2 < NT) {
            STAGE_A(t + 2, 0); STAGE_A(t + 2, 1); STAGE_A(t + 2, 2); STAGE_A(t + 2, 3);
            STAGE_B(t + 2, 0); STAGE_B(t + 2, 1);
        }

        // ---- half 0: k 0..31 ----
        short8 a0[4], b0[4];
#pragma unroll
        for (int nt = 0; nt < 4; ++nt)
            b0[nt] = *(const short8*)&bs[(wn * 64 + nt * 16 + mrow) * 64 + phys0];
#pragma unroll
        for (int mt = 0; mt < 4; ++mt)
            a0[mt] = *(const short8*)&as[(wm * 64 + mt * 16 + mrow) * 64 + phys0];
        __builtin_amdgcn_s_setprio(1);
#pragma unroll
        for (int mt = 0; mt < 4; ++mt)
#pragma unroll
            for (int nt = 0; nt < 4; ++nt)
                acc[mt][nt] = __builtin_amdgcn_mfma_f32_16x16x32_bf16(a0[mt], b0[nt],
                                                                      acc[mt][nt], 0, 0, 0);
        __builtin_amdgcn_s_setprio(0);

        // ---- half 1: k 32..63 ----
        short8 a1[4], b1[4];
#pragma unroll
        for (int nt = 0; nt < 4; ++nt)
            b1[nt] = *(const short8*)&bs[(wn * 64 + nt * 16 + mrow) * 64 + phys1];
#pragma unroll
        for (int mt = 0; mt < 4; ++mt)
            a1[mt] = *(const short8*)&as[(wm * 64 + mt * 16 + mrow) * 64 + phys1];
        __builtin_amdgcn_s_setprio(1);
#pragma unroll
        for (int mt = 0; mt < 4; ++mt)
#pragma unroll
            for (int nt = 0; nt < 4; ++nt)
                acc[mt][nt] = __builtin_amdgcn_mfma_f32_16x16x32_bf16(a1[mt], b1[nt],
                                                                      acc[mt][nt], 0, 0, 0);
        __builtin_amdgcn_s_setprio(0);
        // no trailing barrier: next iter's vmcnt + s_barrier closes the tile
    }
#undef STAGE_A
#undef STAGE_B

    // epilogue: C/D layout col=lane&15, row=(lane>>4)*4+reg
    const int colb = n0 + wn * 64;
    const int r_quad = colb / dout;          // relation of this 64-col quadrant
    if (sn && r_quad >= R_REL) return;       // zero-pad columns: skip store
    const int col = colb + (lane & 15);
    const int rb0 = m0 + wm * 64 + (lane >> 4) * 4;
#pragma unroll
    for (int mt = 0; mt < 4; ++mt) {
#pragma unroll
        for (int reg = 0; reg < 4; ++reg) {
            int row = rb0 + mt * 16 + reg;
            if (row < M) {
                float rs = sn ? sn[(size_t)r_quad * N_NODES + row] : 1.0f;
#pragma unroll
                for (int nt = 0; nt < 4; ++nt)
                    C[(size_t)row * NdPad + col + nt * 16] = f2b(acc[mt][nt][reg] * rs);
            }
        }
    }
}

// ---------------- fused 3-relation ELL gather + bias-sum + optional ReLU ----------------
__global__ void gather3_kernel(const unsigned short* __restrict__ hr, int S8, int d8,
                               const int* __restrict__ ell, const int* __restrict__ incnt,
                               const float* __restrict__ dn, const float* __restrict__ bias,
                               unsigned short* __restrict__ outh,
                               int lgc, int total, int do_relu, int dout) {
    int i = blockIdx.x * blockDim.x + threadIdx.x;
    if (i >= total) return;
    int d = i >> lgc;
    int c = i & ((1 << lgc) - 1);
    float acc[8] = {0.f, 0.f, 0.f, 0.f, 0.f, 0.f, 0.f, 0.f};
    const ushort8* hr8 = (const ushort8*)hr;
#pragma unroll
    for (int r = 0; r < R_REL; ++r) {
        int nr = incnt[r * N_NODES + d];
        nr = nr < ELL_CAP ? nr : ELL_CAP;
        size_t base = (size_t)(r * N_NODES + d) << 5;
        float a[8] = {0.f, 0.f, 0.f, 0.f, 0.f, 0.f, 0.f, 0.f};
        for (int k = 0; k < nr; ++k) {
            int s = ell[base + k];
            ushort8 v = hr8[(size_t)s * S8 + r * d8 + c];
#pragma unroll
            for (int j = 0; j < 8; ++j) a[j] += b2f(v[j]);
        }
        float dnd = dn[r * N_NODES + d];
#pragma unroll
        for (int j = 0; j < 8; ++j) acc[j] += dnd * a[j];
    }
    int f = c << 3;
#pragma unroll
    for (int j = 0; j < 8; ++j)
        acc[j] += bias[f + j] + bias[dout + f + j] + bias[2 * dout + f + j];
    if (do_relu) {
#pragma unroll
        for (int j = 0; j < 8; ++j) acc[j] = fmaxf(acc[j], 0.f);
    }
    ushort8 o;
#pragma unroll
    for (int j = 0; j < 8; ++j) o[j] = f2b(acc[j]);
    ((ushort8*)outh)[i] = o;
}

// ---------------- edge scores from UV: score = Wp2 . relu(U[s]+V[d]+bp1) + bp2 ----------
__global__ __launch_bounds__(256) void edge_score_kernel(
        const unsigned short* __restrict__ UV,
        const int* __restrict__ pos_src, const int* __restrict__ pos_dst,
        const int* __restrict__ neg_src, const int* __restrict__ neg_dst,
        const float* __restrict__ bp1, const float* __restrict__ Wp2,
        const float* __restrict__ bp2, float* __restrict__ outp) {
    __shared__ float sb[64], sw[64];
    int t = threadIdx.x;
    if (t < 64) { sb[t] = bp1[t]; sw[t] = Wp2[t]; }
    __syncthreads();
    int i = blockIdx.x * blockDim.x + t;
    if (i >= 2 * EP_EDGES) return;
    int s, d;
    if (i < EP_EDGES) { s = pos_src[i]; d = pos_dst[i]; }
    else              { s = neg_src[i - EP_EDGES]; d = neg_dst[i - EP_EDGES]; }
    const ushort8* UV8 = (const ushort8*)UV;
    float acc = bp2[0];
#pragma unroll
    for (int jv = 0; jv < 8; ++jv) {
        ushort8 u = UV8[(size_t)s * 16 + jv];
        ushort8 v = UV8[(size_t)d * 16 + 8 + jv];
#pragma unroll
        for (int j = 0; j < 8; ++j) {
            float z = b2f(u[j]) + b2f(v[j]) + sb[jv * 8 + j];
            acc = fmaf(fmaxf(z, 0.f), sw[jv * 8 + j], acc);
        }
    }
    outp[i] = acc;
}

extern "C" void kernel_launch(void* const* d_in, const int* in_sizes, int n_in,
                              void* d_out, int out_size, void* d_ws, size_t ws_size,
                              hipStream_t stream) {
    const float* x       = (const float*)d_in[0];
    const int*   rel_src = (const int*)d_in[1];
    const int*   rel_dst = (const int*)d_in[2];
    const int*   pos_src = (const int*)d_in[3];
    const int*   pos_dst = (const int*)d_in[4];
    const int*   neg_src = (const int*)d_in[5];
    const int*   neg_dst = (const int*)d_in[6];
    const float* W[4]    = {(const float*)d_in[7],  (const float*)d_in[9],
                            (const float*)d_in[11], (const float*)d_in[13]};
    const float* bias[4] = {(const float*)d_in[8],  (const float*)d_in[10],
                            (const float*)d_in[12], (const float*)d_in[14]};
    const float* Wp1 = (const float*)d_in[15];
    const float* bp1 = (const float*)d_in[16];
    const float* Wp2 = (const float*)d_in[17];
    const float* bp2 = (const float*)d_in[18];
    float* out = (float*)d_out;

    // workspace layout (bf16 buffers padded +256 rows for OOB tile reads, BM=256)
    size_t NP = (size_t)(N_NODES + 256);
    unsigned short* xb  = (unsigned short*)d_ws;          // NP x 512 (reused for UV later)
    unsigned short* h0  = xb + NP * 512;                  // NP x 512
    unsigned short* h1  = h0 + NP * 512;                  // NP x 256
    unsigned short* hr  = h1 + NP * 256;                  // N x 1536 max (fused C)
    unsigned short* Wt0 = hr + (size_t)R_REL * N_NODES * 512;
    unsigned short* Wt1 = Wt0 + 786432;
    unsigned short* Wt2 = Wt1 + 393216;
    unsigned short* Wt3 = Wt2 + 98304;
    unsigned short* But = Wt3 + 32768;                    // 128*64
    float* sn   = (float*)(But + 128 * 64);
    float* dn   = sn + (size_t)R_REL * N_NODES;
    int* outcnt = (int*)(dn + (size_t)R_REL * N_NODES);
    int* incnt  = outcnt + (size_t)R_REL * N_NODES;
    int* ell    = incnt + (size_t)R_REL * N_NODES;        // 3*N*32 ints
    unsigned short* UV = xb;                              // N x 128 (after layers done)
    const unsigned short* Wt[4] = {Wt0, Wt1, Wt2, Wt3};

    hipMemsetAsync(outcnt, 0, sizeof(int) * 2 * R_REL * N_NODES, stream);
    count_fill_kernel<<<cdiv_h(R_REL * E_EDGES, 256), 256, 0, stream>>>(
        rel_src, rel_dst, outcnt, incnt, ell);
    norm_kernel<<<cdiv_h(2 * R_REL * N_NODES, 256), 256, 0, stream>>>(
        outcnt, sn, 2 * R_REL * N_NODES);

    f2b8_kernel<<<cdiv_h(N_NODES * 512 / 8, 256), 256, 0, stream>>>(x, xb, N_NODES * 512 / 8);
    prep_weights_kernel<<<cdiv_h(1318912, 256), 256, 0, stream>>>(
        W[0], W[1], W[2], W[3], Wp1, Wt0, Wt1, Wt2, Wt3, But);

    const int dims[5]  = {512, 512, 256, 128, 64};
    const int ndpad[4] = {1536, 768, 384, 256};   // 3*dout padded to x128
    unsigned short* hbufs[4] = {h0, h1, h0, h1};
    const unsigned short* hcur = xb;
    for (int l = 0; l < 4; ++l) {
        int din = dims[l], dout = dims[l + 1], NdPad = ndpad[l];
        unsigned short* hnext = hbufs[l];
        dim3 grid(NdPad / 128, cdiv_h(N_NODES, 256));
        gemm_bf16_fused<<<grid, 512, 0, stream>>>(hcur, Wt[l], hr, sn, N_NODES, din, NdPad, dout);
        int lgc = (dout == 512) ? 6 : (dout == 256) ? 5 : (dout == 128) ? 4 : 3; // log2(dout/8)
        int total = N_NODES << lgc;
        gather3_kernel<<<cdiv_h(total, 256), 256, 0, stream>>>(
            hr, NdPad / 8, dout / 8, ell, incnt, dn, bias[l], hnext, lgc, total,
            (l < 3) ? 1 : 0, dout);
        hcur = hnext;
    }

    // UV = h_final @ [Wp1_top | Wp1_bot]  (M=N, K=64, Nd=128)
    dim3 uvgrid(1, cdiv_h(N_NODES, 256));
    gemm_bf16_fused<<<uvgrid, 512, 0, stream>>>(hcur, But, UV, nullptr, N_NODES, 64, 128, 128);

    edge_score_kernel<<<cdiv_h(2 * EP_EDGES, 256), 256, 0, stream>>>(
        UV, pos_src, pos_dst, neg_src, neg_dst, bp1, Wp2, bp2, out);
}

// Round 4
// 552.782 us; speedup vs baseline: 1.1400x; 1.1400x over previous
//
#include <hip/hip_runtime.h>

#define N_NODES  50000
#define R_REL    3
#define E_EDGES  50000
#define EP_EDGES 100000
#define ELL_CAP  32

typedef __attribute__((ext_vector_type(8))) short  short8;
typedef __attribute__((ext_vector_type(8))) unsigned short ushort8;
typedef __attribute__((ext_vector_type(4))) float  floatx4;

static inline int cdiv_h(int a, int b) { return (a + b - 1) / b; }

__device__ inline unsigned short f2b(float f) {
    union { float f; unsigned u; } v; v.f = f;
    return (unsigned short)((v.u + 0x7FFF + ((v.u >> 16) & 1)) >> 16);
}
__device__ inline float b2f(unsigned short h) {
    union { unsigned u; float f; } v; v.u = ((unsigned)h) << 16;
    return v.f;
}

#define GLDS16(gp, lp) __builtin_amdgcn_global_load_lds( \
    (const __attribute__((address_space(1))) void*)(gp), \
    (__attribute__((address_space(3))) void*)(lp), 16, 0, 0)

// ---------------- degree count + ELL fill ----------------
__global__ void count_fill_kernel(const int* __restrict__ src, const int* __restrict__ dst,
                                  int* __restrict__ outcnt, int* __restrict__ incnt,
                                  int* __restrict__ ell) {
    int i = blockIdx.x * blockDim.x + threadIdx.x;
    if (i >= R_REL * E_EDGES) return;
    int r = i / E_EDGES;
    int s = src[i], d = dst[i];
    atomicAdd(&outcnt[r * N_NODES + s], 1);
    int k = atomicAdd(&incnt[r * N_NODES + d], 1);
    if (k < ELL_CAP)
        ell[((size_t)(r * N_NODES + d) << 5) + k] = s;
}

__global__ void norm_kernel(const int* __restrict__ cnt, float* __restrict__ nrm, int n) {
    int i = blockIdx.x * blockDim.x + threadIdx.x;
    if (i < n) nrm[i] = rsqrtf(fmaxf((float)cnt[i], 1.0f));
}

// ---------------- fp32 -> bf16 (8 elems/thread) ----------------
__global__ void f2b8_kernel(const float* __restrict__ in, unsigned short* __restrict__ out,
                            int total8) {
    int i = blockIdx.x * blockDim.x + threadIdx.x;
    if (i >= total8) return;
    float4 a = ((const float4*)in)[2 * i];
    float4 b = ((const float4*)in)[2 * i + 1];
    ushort8 o;
    o[0] = f2b(a.x); o[1] = f2b(a.y); o[2] = f2b(a.z); o[3] = f2b(a.w);
    o[4] = f2b(b.x); o[5] = f2b(b.y); o[6] = f2b(b.z); o[7] = f2b(b.w);
    ((ushort8*)out)[i] = o;
}

// ---------------- weight transposes (4 layers + Wp1) + summed-bias, one launch --------
// Wt_l[nall][k] = W_l[r][k][n] with nall = r*dout+n; L3 pads rows 192..255 with 0.
// Tail threads also write bsum[960]: per-layer sum of the 3 relation biases.
__global__ void prep_weights_kernel(
        const float* __restrict__ W0, const float* __restrict__ W1,
        const float* __restrict__ W2, const float* __restrict__ W3,
        const float* __restrict__ Wp1,
        const float* __restrict__ B0, const float* __restrict__ B1,
        const float* __restrict__ B2, const float* __restrict__ B3,
        unsigned short* __restrict__ Wt0, unsigned short* __restrict__ Wt1,
        unsigned short* __restrict__ Wt2, unsigned short* __restrict__ Wt3,
        unsigned short* __restrict__ But, float* __restrict__ bsum) {
    int i = blockIdx.x * blockDim.x + threadIdx.x;
    if (i < 786432) {                       // L0: K=512 dout=512 rows=1536 (no pad)
        int k = i & 511, nall = i >> 9, r = nall >> 9, n = nall & 511;
        Wt0[i] = f2b(W0[(((size_t)r << 9) + k) * 512 + n]);
    } else if (i < 1179648) {               // L1: K=512 dout=256 rows=768
        int j = i - 786432;
        int k = j & 511, nall = j >> 9, r = nall >> 8, n = nall & 255;
        Wt1[j] = f2b(W1[(((size_t)r << 9) + k) * 256 + n]);
    } else if (i < 1277952) {               // L2: K=256 dout=128 rows=384
        int j = i - 1179648;
        int k = j & 255, nall = j >> 8, r = nall >> 7, n = nall & 127;
        Wt2[j] = f2b(W2[(((size_t)r << 8) + k) * 128 + n]);
    } else if (i < 1310720) {               // L3: K=128 dout=64 rows=256 (pad 192..255)
        int j = i - 1277952;
        int k = j & 127, nall = j >> 7, r = nall >> 6, n = nall & 63;
        Wt3[j] = (r < R_REL) ? f2b(W3[(((size_t)r << 7) + k) * 64 + n]) : (unsigned short)0;
    } else if (i < 1318912) {               // Wp1 -> But[128][64]
        int j = i - 1310720;
        int k = j & 63, jo = j >> 6, jj = jo & 63, half = jo >> 6;
        But[j] = f2b(Wp1[(size_t)(half * 64 + k) * 64 + jj]);
    } else if (i < 1319872) {               // bsum[960]: L0 [0,512) L1 [512,768) L2 [768,896) L3 [896,960)
        int j = i - 1318912;
        const float* B; int f, dout;
        if (j < 512)      { B = B0; f = j;       dout = 512; }
        else if (j < 768) { B = B1; f = j - 512; dout = 256; }
        else if (j < 896) { B = B2; f = j - 768; dout = 128; }
        else              { B = B3; f = j - 896; dout = 64;  }
        bsum[j] = B[f] + B[dout + f] + B[2 * dout + f];
    }
}

// ---------------- fused MFMA GEMM: C[m][n] = (A[m][:].Bt[n][:]) * sn[n/dout][m] --------
// BM=128 BN=128 BK=64, 256 thr, 4 waves, wave tile 64x64 = 4x4 16x16 tiles.
// A+B staged in LDS (32KB) via global_load_lds; 2 barriers per 64-K step.
// 8-chunk XOR swizzle: LDS[r][p] holds global chunk p^(r&7) -> 2-way bank aliasing
// (free), staging reads contiguous 128B per 8 lanes. K%64==0, NdPad%128==0.
// sn==nullptr -> scale 1, no rel guard. Verified structure (round 0, 118us @ L0);
// rounds 1-3 showed deeper pipelines at 1 block/CU lose the inter-block overlap
// that this 3-blocks/CU shape gets for free (MfmaUtil 29 -> 20-22).
// XCD-locality swizzle: blocks p==j (mod 8) share one m-panel across n-blocks.
__global__ __launch_bounds__(256) void gemm_bf16_fused(
        const unsigned short* __restrict__ A, const unsigned short* __restrict__ Bt,
        unsigned short* __restrict__ C, const float* __restrict__ sn,
        int M, int K, int NdPad, int dout) {
    __shared__ unsigned short As[8192];   // [128][64]
    __shared__ unsigned short Bs[8192];   // [128][64]

    const int nN = gridDim.x, nM = gridDim.y;
    int p = blockIdx.y * nN + blockIdx.x;
    const int nig = nN << 3;
    int group = p / nig;
    int rem = p - group * nig;
    int gs = nM - (group << 3); if (gs > 8) gs = 8;
    int mb = (group << 3) + rem % gs;
    int nb = rem / gs;
    const int m0 = mb * 128, n0 = nb * 128;

    const int tid  = threadIdx.x;
    const int w    = tid >> 6;
    const int lane = tid & 63;
    const int wm   = w & 1;            // 64-row half
    const int wn   = w >> 1;           // 64-col half
    const int lrow8 = lane >> 3;       // 0..7 staging row within 8-row chunk
    const int cs    = ((lane & 7) ^ lrow8) << 3;  // swizzled src chunk offset (ushorts)

    floatx4 acc[4][4];
#pragma unroll
    for (int i = 0; i < 4; ++i)
#pragma unroll
        for (int j = 0; j < 4; ++j) acc[i][j] = (floatx4){0.f, 0.f, 0.f, 0.f};

    const int mrow  = lane & 15;
    const int phys0 = ((lane >> 4) ^ (lane & 7)) << 3;   // h=0 read offset (ushorts)
    const int phys1 = phys0 ^ 32;                        // h=1 (c_log+4 -> ^4 chunks)

    for (int k0 = 0; k0 < K; k0 += 64) {
#pragma unroll
        for (int i = 0; i < 4; ++i) {
            int rr = i * 32 + 8 * w + lrow8;
            GLDS16(A  + (size_t)(m0 + rr) * K + k0 + cs, As + (i * 32 + 8 * w) * 64);
        }
#pragma unroll
        for (int i = 0; i < 4; ++i) {
            int rr = i * 32 + 8 * w + lrow8;
            GLDS16(Bt + (size_t)(n0 + rr) * K + k0 + cs, Bs + (i * 32 + 8 * w) * 64);
        }
        __syncthreads();

#pragma unroll
        for (int h = 0; h < 2; ++h) {
            const int ph = h ? phys1 : phys0;
            short8 a[4], b[4];
#pragma unroll
            for (int nt = 0; nt < 4; ++nt)
                b[nt] = *(const short8*)&Bs[(wn * 64 + nt * 16 + mrow) * 64 + ph];
#pragma unroll
            for (int mt = 0; mt < 4; ++mt)
                a[mt] = *(const short8*)&As[(wm * 64 + mt * 16 + mrow) * 64 + ph];
#pragma unroll
            for (int mt = 0; mt < 4; ++mt)
#pragma unroll
                for (int nt = 0; nt < 4; ++nt)
                    acc[mt][nt] = __builtin_amdgcn_mfma_f32_16x16x32_bf16(a[mt], b[nt],
                                                                          acc[mt][nt], 0, 0, 0);
        }
        __syncthreads();
    }

    // epilogue: C/D layout col=lane&15, row=(lane>>4)*4+reg
    const int colb = n0 + wn * 64;
    const int r_quad = colb / dout;          // relation of this 64-col quadrant
    if (sn && r_quad >= R_REL) return;       // zero-pad columns: skip store
    const int col = colb + (lane & 15);
    const int rb0 = m0 + wm * 64 + (lane >> 4) * 4;
#pragma unroll
    for (int mt = 0; mt < 4; ++mt) {
        // rows rb0+mt*16 .. +3 are consecutive & 4-aligned -> one float4 sn load
        // (tail rows >= M read into the adjacent dn allocation; guarded unused)
        float4 rsv;
        if (sn) rsv = *(const float4*)&sn[(size_t)r_quad * N_NODES + rb0 + mt * 16];
        else    rsv = (float4){1.f, 1.f, 1.f, 1.f};
        const float* rsp = (const float*)&rsv;
#pragma unroll
        for (int reg = 0; reg < 4; ++reg) {
            int row = rb0 + mt * 16 + reg;
            if (row < M) {
                float rs = rsp[reg];
#pragma unroll
                for (int nt = 0; nt < 4; ++nt)
                    C[(size_t)row * NdPad + col + nt * 16] = f2b(acc[mt][nt][reg] * rs);
            }
        }
    }
}

// ---------------- fused 3-relation ELL gather + summed-bias + optional ReLU ------------
// hr rows are [rel0 | rel1 | rel2 | pad] with row stride S8 ushort8-chunks.
__global__ void gather3_kernel(const unsigned short* __restrict__ hr, int S8, int d8,
                               const int* __restrict__ ell, const int* __restrict__ incnt,
                               const float* __restrict__ dn, const float* __restrict__ bsum,
                               unsigned short* __restrict__ outh,
                               int lgc, int total, int do_relu) {
    int i = blockIdx.x * blockDim.x + threadIdx.x;
    if (i >= total) return;
    int d = i >> lgc;
    int c = i & ((1 << lgc) - 1);
    float acc[8] = {0.f, 0.f, 0.f, 0.f, 0.f, 0.f, 0.f, 0.f};
    const ushort8* hr8 = (const ushort8*)hr;
#pragma unroll
    for (int r = 0; r < R_REL; ++r) {
        int nr = incnt[r * N_NODES + d];
        nr = nr < ELL_CAP ? nr : ELL_CAP;
        size_t base = (size_t)(r * N_NODES + d) << 5;
        float a[8] = {0.f, 0.f, 0.f, 0.f, 0.f, 0.f, 0.f, 0.f};
        for (int k = 0; k < nr; ++k) {
            int s = ell[base + k];
            ushort8 v = hr8[(size_t)s * S8 + r * d8 + c];
#pragma unroll
            for (int j = 0; j < 8; ++j) a[j] += b2f(v[j]);
        }
        float dnd = dn[r * N_NODES + d];
#pragma unroll
        for (int j = 0; j < 8; ++j) acc[j] += dnd * a[j];
    }
    int f = c << 3;
#pragma unroll
    for (int j = 0; j < 8; ++j) acc[j] += bsum[f + j];
    if (do_relu) {
#pragma unroll
        for (int j = 0; j < 8; ++j) acc[j] = fmaxf(acc[j], 0.f);
    }
    ushort8 o;
#pragma unroll
    for (int j = 0; j < 8; ++j) o[j] = f2b(acc[j]);
    ((ushort8*)outh)[i] = o;
}

// ---------------- edge scores from UV: score = Wp2 . relu(U[s]+V[d]+bp1) + bp2 ----------
__global__ __launch_bounds__(256) void edge_score_kernel(
        const unsigned short* __restrict__ UV,
        const int* __restrict__ pos_src, const int* __restrict__ pos_dst,
        const int* __restrict__ neg_src, const int* __restrict__ neg_dst,
        const float* __restrict__ bp1, const float* __restrict__ Wp2,
        const float* __restrict__ bp2, float* __restrict__ outp) {
    __shared__ float sb[64], sw[64];
    int t = threadIdx.x;
    if (t < 64) { sb[t] = bp1[t]; sw[t] = Wp2[t]; }
    __syncthreads();
    int i = blockIdx.x * blockDim.x + t;
    if (i >= 2 * EP_EDGES) return;
    int s, d;
    if (i < EP_EDGES) { s = pos_src[i]; d = pos_dst[i]; }
    else              { s = neg_src[i - EP_EDGES]; d = neg_dst[i - EP_EDGES]; }
    const ushort8* UV8 = (const ushort8*)UV;
    float acc = bp2[0];
#pragma unroll
    for (int jv = 0; jv < 8; ++jv) {
        ushort8 u = UV8[(size_t)s * 16 + jv];
        ushort8 v = UV8[(size_t)d * 16 + 8 + jv];
#pragma unroll
        for (int j = 0; j < 8; ++j) {
            float z = b2f(u[j]) + b2f(v[j]) + sb[jv * 8 + j];
            acc = fmaf(fmaxf(z, 0.f), sw[jv * 8 + j], acc);
        }
    }
    outp[i] = acc;
}

extern "C" void kernel_launch(void* const* d_in, const int* in_sizes, int n_in,
                              void* d_out, int out_size, void* d_ws, size_t ws_size,
                              hipStream_t stream) {
    const float* x       = (const float*)d_in[0];
    const int*   rel_src = (const int*)d_in[1];
    const int*   rel_dst = (const int*)d_in[2];
    const int*   pos_src = (const int*)d_in[3];
    const int*   pos_dst = (const int*)d_in[4];
    const int*   neg_src = (const int*)d_in[5];
    const int*   neg_dst = (const int*)d_in[6];
    const float* W[4]    = {(const float*)d_in[7],  (const float*)d_in[9],
                            (const float*)d_in[11], (const float*)d_in[13]};
    const float* bias[4] = {(const float*)d_in[8],  (const float*)d_in[10],
                            (const float*)d_in[12], (const float*)d_in[14]};
    const float* Wp1 = (const float*)d_in[15];
    const float* bp1 = (const float*)d_in[16];
    const float* Wp2 = (const float*)d_in[17];
    const float* bp2 = (const float*)d_in[18];
    float* out = (float*)d_out;

    // workspace layout (bf16 buffers padded +128 rows for OOB tile reads, BM=128)
    size_t NP = (size_t)(N_NODES + 128);
    unsigned short* xb  = (unsigned short*)d_ws;          // NP x 512 (reused for UV later)
    unsigned short* h0  = xb + NP * 512;                  // NP x 512
    unsigned short* h1  = h0 + NP * 512;                  // NP x 256
    unsigned short* hr  = h1 + NP * 256;                  // N x 1536 max (fused C)
    unsigned short* Wt0 = hr + (size_t)R_REL * N_NODES * 512;
    unsigned short* Wt1 = Wt0 + 786432;
    unsigned short* Wt2 = Wt1 + 393216;
    unsigned short* Wt3 = Wt2 + 98304;
    unsigned short* But = Wt3 + 32768;                    // 128*64
    float* bsum = (float*)(But + 128 * 64);               // 960 summed biases
    float* sn   = bsum + 960;
    float* dn   = sn + (size_t)R_REL * N_NODES;
    int* outcnt = (int*)(dn + (size_t)R_REL * N_NODES);
    int* incnt  = outcnt + (size_t)R_REL * N_NODES;
    int* ell    = incnt + (size_t)R_REL * N_NODES;        // 3*N*32 ints
    unsigned short* UV = xb;                              // N x 128 (after layers done)
    const unsigned short* Wt[4] = {Wt0, Wt1, Wt2, Wt3};
    const int boff[4] = {0, 512, 768, 896};

    hipMemsetAsync(outcnt, 0, sizeof(int) * 2 * R_REL * N_NODES, stream);
    count_fill_kernel<<<cdiv_h(R_REL * E_EDGES, 256), 256, 0, stream>>>(
        rel_src, rel_dst, outcnt, incnt, ell);
    // sn,dn contiguous and outcnt,incnt contiguous -> one launch covers both
    norm_kernel<<<cdiv_h(2 * R_REL * N_NODES, 256), 256, 0, stream>>>(
        outcnt, sn, 2 * R_REL * N_NODES);

    f2b8_kernel<<<cdiv_h(N_NODES * 512 / 8, 256), 256, 0, stream>>>(x, xb, N_NODES * 512 / 8);
    prep_weights_kernel<<<cdiv_h(1319872, 256), 256, 0, stream>>>(
        W[0], W[1], W[2], W[3], Wp1, bias[0], bias[1], bias[2], bias[3],
        Wt0, Wt1, Wt2, Wt3, But, bsum);

    const int dims[5]  = {512, 512, 256, 128, 64};
    const int ndpad[4] = {1536, 768, 384, 256};   // 3*dout padded to x128
    unsigned short* hbufs[4] = {h0, h1, h0, h1};
    const unsigned short* hcur = xb;
    for (int l = 0; l < 4; ++l) {
        int din = dims[l], dout = dims[l + 1], NdPad = ndpad[l];
        unsigned short* hnext = hbufs[l];
        dim3 grid(NdPad / 128, cdiv_h(N_NODES, 128));
        gemm_bf16_fused<<<grid, 256, 0, stream>>>(hcur, Wt[l], hr, sn, N_NODES, din, NdPad, dout);
        int lgc = (dout == 512) ? 6 : (dout == 256) ? 5 : (dout == 128) ? 4 : 3; // log2(dout/8)
        int total = N_NODES << lgc;
        gather3_kernel<<<cdiv_h(total, 256), 256, 0, stream>>>(
            hr, NdPad / 8, dout / 8, ell, incnt, dn, bsum + boff[l], hnext, lgc, total,
            (l < 3) ? 1 : 0);
        hcur = hnext;
    }

    // UV = h_final @ [Wp1_top | Wp1_bot]  (M=N, K=64, Nd=128)
    dim3 uvgrid(1, cdiv_h(N_NODES, 128));
    gemm_bf16_fused<<<uvgrid, 256, 0, stream>>>(hcur, But, UV, nullptr, N_NODES, 64, 128, 128);

    edge_score_kernel<<<cdiv_h(2 * EP_EDGES, 256), 256, 0, stream>>>(
        UV, pos_src, pos_dst, neg_src, neg_dst, bp1, Wp2, bp2, out);
}

// Round 5
// 541.297 us; speedup vs baseline: 1.1642x; 1.0212x over previous
//
#include <hip/hip_runtime.h>

#define N_NODES  50000
#define R_REL    3
#define E_EDGES  50000
#define EP_EDGES 100000
#define ELL_CAP  32

typedef __attribute__((ext_vector_type(8))) short  short8;
typedef __attribute__((ext_vector_type(8))) unsigned short ushort8;
typedef __attribute__((ext_vector_type(4))) float  floatx4;

static inline int cdiv_h(int a, int b) { return (a + b - 1) / b; }

__device__ inline unsigned short f2b(float f) {
    union { float f; unsigned u; } v; v.f = f;
    return (unsigned short)((v.u + 0x7FFF + ((v.u >> 16) & 1)) >> 16);
}
__device__ inline float b2f(unsigned short h) {
    union { unsigned u; float f; } v; v.u = ((unsigned)h) << 16;
    return v.f;
}

#define GLDS16(gp, lp) __builtin_amdgcn_global_load_lds( \
    (const __attribute__((address_space(1))) void*)(gp), \
    (__attribute__((address_space(3))) void*)(lp), 16, 0, 0)

// ---------------- degree count + ELL fill ----------------
__global__ void count_fill_kernel(const int* __restrict__ src, const int* __restrict__ dst,
                                  int* __restrict__ outcnt, int* __restrict__ incnt,
                                  int* __restrict__ ell) {
    int i = blockIdx.x * blockDim.x + threadIdx.x;
    if (i >= R_REL * E_EDGES) return;
    int r = i / E_EDGES;
    int s = src[i], d = dst[i];
    atomicAdd(&outcnt[r * N_NODES + s], 1);
    int k = atomicAdd(&incnt[r * N_NODES + d], 1);
    if (k < ELL_CAP)
        ell[((size_t)(r * N_NODES + d) << 5) + k] = s;
}

// ---------------- fused aux pass: norms + x->bf16 + weight transposes + bsum ------------
// One launch for everything that depends only on count_fill:
//   [0, 300000)            : sn/dn = rsqrt(max(cnt,1))            (outcnt/incnt contiguous)
//   [300000, 3500000)      : x fp32 -> bf16, 8 elems/thread
//   [3500000, 4819872)     : weight transposes (4 layers + Wp1) + bsum[960]
#define AUX_NORM 300000
#define AUX_F2B  3200000
#define AUX_PREP 1319872
__global__ void aux_kernel(
        const int* __restrict__ cnt, float* __restrict__ nrm,
        const float* __restrict__ x, unsigned short* __restrict__ xb,
        const float* __restrict__ W0, const float* __restrict__ W1,
        const float* __restrict__ W2, const float* __restrict__ W3,
        const float* __restrict__ Wp1,
        const float* __restrict__ B0, const float* __restrict__ B1,
        const float* __restrict__ B2, const float* __restrict__ B3,
        unsigned short* __restrict__ Wt0, unsigned short* __restrict__ Wt1,
        unsigned short* __restrict__ Wt2, unsigned short* __restrict__ Wt3,
        unsigned short* __restrict__ But, float* __restrict__ bsum) {
    int t = blockIdx.x * blockDim.x + threadIdx.x;
    if (t < AUX_NORM) {
        nrm[t] = rsqrtf(fmaxf((float)cnt[t], 1.0f));
        return;
    }
    t -= AUX_NORM;
    if (t < AUX_F2B) {
        float4 a = ((const float4*)x)[2 * t];
        float4 b = ((const float4*)x)[2 * t + 1];
        ushort8 o;
        o[0] = f2b(a.x); o[1] = f2b(a.y); o[2] = f2b(a.z); o[3] = f2b(a.w);
        o[4] = f2b(b.x); o[5] = f2b(b.y); o[6] = f2b(b.z); o[7] = f2b(b.w);
        ((ushort8*)xb)[t] = o;
        return;
    }
    int i = t - AUX_F2B;
    if (i >= AUX_PREP) return;
    if (i < 786432) {                       // L0: K=512 dout=512 rows=1536 (no pad)
        int k = i & 511, nall = i >> 9, r = nall >> 9, n = nall & 511;
        Wt0[i] = f2b(W0[(((size_t)r << 9) + k) * 512 + n]);
    } else if (i < 1179648) {               // L1: K=512 dout=256 rows=768
        int j = i - 786432;
        int k = j & 511, nall = j >> 9, r = nall >> 8, n = nall & 255;
        Wt1[j] = f2b(W1[(((size_t)r << 9) + k) * 256 + n]);
    } else if (i < 1277952) {               // L2: K=256 dout=128 rows=384
        int j = i - 1179648;
        int k = j & 255, nall = j >> 8, r = nall >> 7, n = nall & 127;
        Wt2[j] = f2b(W2[(((size_t)r << 8) + k) * 128 + n]);
    } else if (i < 1310720) {               // L3: K=128 dout=64 rows=256 (pad 192..255)
        int j = i - 1277952;
        int k = j & 127, nall = j >> 7, r = nall >> 6, n = nall & 63;
        Wt3[j] = (r < R_REL) ? f2b(W3[(((size_t)r << 7) + k) * 64 + n]) : (unsigned short)0;
    } else if (i < 1318912) {               // Wp1 -> But[128][64]
        int j = i - 1310720;
        int k = j & 63, jo = j >> 6, jj = jo & 63, half = jo >> 6;
        But[j] = f2b(Wp1[(size_t)(half * 64 + k) * 64 + jj]);
    } else {                                // bsum[960]: L0 [0,512) L1 [512,768) L2 [768,896) L3 [896,960)
        int j = i - 1318912;
        const float* B; int f, dout;
        if (j < 512)      { B = B0; f = j;       dout = 512; }
        else if (j < 768) { B = B1; f = j - 512; dout = 256; }
        else if (j < 896) { B = B2; f = j - 768; dout = 128; }
        else              { B = B3; f = j - 896; dout = 64;  }
        bsum[j] = B[f] + B[dout + f] + B[2 * dout + f];
    }
}

// ---------------- fused MFMA GEMM: C[m][n] = (A[m][:].Bt[n][:]) * sn[n/dout][m] --------
// BM=128 BN=128 BK=64, 256 thr, 4 waves, wave tile 64x64 = 4x4 16x16 tiles.
// A+B staged in LDS (32KB) via global_load_lds; 2 barriers per 64-K step.
// 8-chunk XOR swizzle: LDS[r][p] holds global chunk p^(r&7) -> 2-way bank aliasing
// (free), staging reads contiguous 128B per 8 lanes. K%64==0, NdPad%128==0.
// sn==nullptr -> scale 1, no rel guard. Verified structure (round 0/4, ~112us @ L0);
// rounds 1-3 showed deeper pipelines at 1 block/CU lose the inter-block overlap
// that this ~2.3-blocks/CU shape gets for free (MfmaUtil 30 -> 20-22). Frozen.
// XCD-locality swizzle: blocks p==j (mod 8) share one m-panel across n-blocks.
__global__ __launch_bounds__(256) void gemm_bf16_fused(
        const unsigned short* __restrict__ A, const unsigned short* __restrict__ Bt,
        unsigned short* __restrict__ C, const float* __restrict__ sn,
        int M, int K, int NdPad, int dout) {
    __shared__ unsigned short As[8192];   // [128][64]
    __shared__ unsigned short Bs[8192];   // [128][64]

    const int nN = gridDim.x, nM = gridDim.y;
    int p = blockIdx.y * nN + blockIdx.x;
    const int nig = nN << 3;
    int group = p / nig;
    int rem = p - group * nig;
    int gs = nM - (group << 3); if (gs > 8) gs = 8;
    int mb = (group << 3) + rem % gs;
    int nb = rem / gs;
    const int m0 = mb * 128, n0 = nb * 128;

    const int tid  = threadIdx.x;
    const int w    = tid >> 6;
    const int lane = tid & 63;
    const int wm   = w & 1;            // 64-row half
    const int wn   = w >> 1;           // 64-col half
    const int lrow8 = lane >> 3;       // 0..7 staging row within 8-row chunk
    const int cs    = ((lane & 7) ^ lrow8) << 3;  // swizzled src chunk offset (ushorts)

    floatx4 acc[4][4];
#pragma unroll
    for (int i = 0; i < 4; ++i)
#pragma unroll
        for (int j = 0; j < 4; ++j) acc[i][j] = (floatx4){0.f, 0.f, 0.f, 0.f};

    const int mrow  = lane & 15;
    const int phys0 = ((lane >> 4) ^ (lane & 7)) << 3;   // h=0 read offset (ushorts)
    const int phys1 = phys0 ^ 32;                        // h=1 (c_log+4 -> ^4 chunks)

    for (int k0 = 0; k0 < K; k0 += 64) {
#pragma unroll
        for (int i = 0; i < 4; ++i) {
            int rr = i * 32 + 8 * w + lrow8;
            GLDS16(A  + (size_t)(m0 + rr) * K + k0 + cs, As + (i * 32 + 8 * w) * 64);
        }
#pragma unroll
        for (int i = 0; i < 4; ++i) {
            int rr = i * 32 + 8 * w + lrow8;
            GLDS16(Bt + (size_t)(n0 + rr) * K + k0 + cs, Bs + (i * 32 + 8 * w) * 64);
        }
        __syncthreads();

#pragma unroll
        for (int h = 0; h < 2; ++h) {
            const int ph = h ? phys1 : phys0;
            short8 a[4], b[4];
#pragma unroll
            for (int nt = 0; nt < 4; ++nt)
                b[nt] = *(const short8*)&Bs[(wn * 64 + nt * 16 + mrow) * 64 + ph];
#pragma unroll
            for (int mt = 0; mt < 4; ++mt)
                a[mt] = *(const short8*)&As[(wm * 64 + mt * 16 + mrow) * 64 + ph];
#pragma unroll
            for (int mt = 0; mt < 4; ++mt)
#pragma unroll
                for (int nt = 0; nt < 4; ++nt)
                    acc[mt][nt] = __builtin_amdgcn_mfma_f32_16x16x32_bf16(a[mt], b[nt],
                                                                          acc[mt][nt], 0, 0, 0);
        }
        __syncthreads();
    }

    // epilogue: C/D layout col=lane&15, row=(lane>>4)*4+reg
    const int colb = n0 + wn * 64;
    const int r_quad = colb / dout;          // relation of this 64-col quadrant
    if (sn && r_quad >= R_REL) return;       // zero-pad columns: skip store
    const int col = colb + (lane & 15);
    const int rb0 = m0 + wm * 64 + (lane >> 4) * 4;
#pragma unroll
    for (int mt = 0; mt < 4; ++mt) {
        // rows rb0+mt*16 .. +3 are consecutive & 4-aligned -> one float4 sn load
        // (tail rows >= M read into the adjacent dn allocation; guarded unused)
        float4 rsv;
        if (sn) rsv = *(const float4*)&sn[(size_t)r_quad * N_NODES + rb0 + mt * 16];
        else    rsv = (float4){1.f, 1.f, 1.f, 1.f};
        const float* rsp = (const float*)&rsv;
#pragma unroll
        for (int reg = 0; reg < 4; ++reg) {
            int row = rb0 + mt * 16 + reg;
            if (row < M) {
                float rs = rsp[reg];
#pragma unroll
                for (int nt = 0; nt < 4; ++nt)
                    C[(size_t)row * NdPad + col + nt * 16] = f2b(acc[mt][nt][reg] * rs);
            }
        }
    }
}

// ---------------- fused 3-relation ELL gather + summed-bias + optional ReLU ------------
// Dual-chunk: each thread handles ushort8-chunks c and c+h8 (h8 = d8/2) of node d.
// Halves thread count vs single-chunk -> amortizes incnt/dn/ell broadcast loads and
// loop overhead over 32B/lane; the two row loads per edge are independent (2x MLP).
// hr rows are [rel0 | rel1 | rel2 | pad] with row stride S8 ushort8-chunks.
__global__ void gather3_kernel(const unsigned short* __restrict__ hr, int S8, int d8,
                               const int* __restrict__ ell, const int* __restrict__ incnt,
                               const float* __restrict__ dn, const float* __restrict__ bsum,
                               unsigned short* __restrict__ outh,
                               int lgh, int total, int do_relu) {
    int i = blockIdx.x * blockDim.x + threadIdx.x;
    if (i >= total) return;
    int d = i >> lgh;
    int c = i & ((1 << lgh) - 1);
    int h8 = 1 << lgh;                       // d8/2
    float a0[8] = {0.f, 0.f, 0.f, 0.f, 0.f, 0.f, 0.f, 0.f};
    float a1[8] = {0.f, 0.f, 0.f, 0.f, 0.f, 0.f, 0.f, 0.f};
    const ushort8* hr8 = (const ushort8*)hr;
#pragma unroll
    for (int r = 0; r < R_REL; ++r) {
        int nr = incnt[r * N_NODES + d];
        nr = nr < ELL_CAP ? nr : ELL_CAP;
        size_t base = (size_t)(r * N_NODES + d) << 5;
        float t0[8] = {0.f, 0.f, 0.f, 0.f, 0.f, 0.f, 0.f, 0.f};
        float t1[8] = {0.f, 0.f, 0.f, 0.f, 0.f, 0.f, 0.f, 0.f};
        for (int k = 0; k < nr; ++k) {
            int s = ell[base + k];
            size_t rowb = (size_t)s * S8 + r * d8 + c;
            ushort8 v0 = hr8[rowb];
            ushort8 v1 = hr8[rowb + h8];
#pragma unroll
            for (int j = 0; j < 8; ++j) { t0[j] += b2f(v0[j]); t1[j] += b2f(v1[j]); }
        }
        float dnd = dn[r * N_NODES + d];
#pragma unroll
        for (int j = 0; j < 8; ++j) { a0[j] += dnd * t0[j]; a1[j] += dnd * t1[j]; }
    }
    int f0 = c << 3, f1 = (c + h8) << 3;
#pragma unroll
    for (int j = 0; j < 8; ++j) { a0[j] += bsum[f0 + j]; a1[j] += bsum[f1 + j]; }
    if (do_relu) {
#pragma unroll
        for (int j = 0; j < 8; ++j) { a0[j] = fmaxf(a0[j], 0.f); a1[j] = fmaxf(a1[j], 0.f); }
    }
    ushort8 o0, o1;
#pragma unroll
    for (int j = 0; j < 8; ++j) { o0[j] = f2b(a0[j]); o1[j] = f2b(a1[j]); }
    size_t ob = ((size_t)d << (lgh + 1)) + c;
    ((ushort8*)outh)[ob]      = o0;
    ((ushort8*)outh)[ob + h8] = o1;
}

// ---------------- edge scores from UV: score = Wp2 . relu(U[s]+V[d]+bp1) + bp2 ----------
__global__ __launch_bounds__(256) void edge_score_kernel(
        const unsigned short* __restrict__ UV,
        const int* __restrict__ pos_src, const int* __restrict__ pos_dst,
        const int* __restrict__ neg_src, const int* __restrict__ neg_dst,
        const float* __restrict__ bp1, const float* __restrict__ Wp2,
        const float* __restrict__ bp2, float* __restrict__ outp) {
    __shared__ float sb[64], sw[64];
    int t = threadIdx.x;
    if (t < 64) { sb[t] = bp1[t]; sw[t] = Wp2[t]; }
    __syncthreads();
    int i = blockIdx.x * blockDim.x + t;
    if (i >= 2 * EP_EDGES) return;
    int s, d;
    if (i < EP_EDGES) { s = pos_src[i]; d = pos_dst[i]; }
    else              { s = neg_src[i - EP_EDGES]; d = neg_dst[i - EP_EDGES]; }
    const ushort8* UV8 = (const ushort8*)UV;
    float acc = bp2[0];
#pragma unroll
    for (int jv = 0; jv < 8; ++jv) {
        ushort8 u = UV8[(size_t)s * 16 + jv];
        ushort8 v = UV8[(size_t)d * 16 + 8 + jv];
#pragma unroll
        for (int j = 0; j < 8; ++j) {
            float z = b2f(u[j]) + b2f(v[j]) + sb[jv * 8 + j];
            acc = fmaf(fmaxf(z, 0.f), sw[jv * 8 + j], acc);
        }
    }
    outp[i] = acc;
}

extern "C" void kernel_launch(void* const* d_in, const int* in_sizes, int n_in,
                              void* d_out, int out_size, void* d_ws, size_t ws_size,
                              hipStream_t stream) {
    const float* x       = (const float*)d_in[0];
    const int*   rel_src = (const int*)d_in[1];
    const int*   rel_dst = (const int*)d_in[2];
    const int*   pos_src = (const int*)d_in[3];
    const int*   pos_dst = (const int*)d_in[4];
    const int*   neg_src = (const int*)d_in[5];
    const int*   neg_dst = (const int*)d_in[6];
    const float* W[4]    = {(const float*)d_in[7],  (const float*)d_in[9],
                            (const float*)d_in[11], (const float*)d_in[13]};
    const float* bias[4] = {(const float*)d_in[8],  (const float*)d_in[10],
                            (const float*)d_in[12], (const float*)d_in[14]};
    const float* Wp1 = (const float*)d_in[15];
    const float* bp1 = (const float*)d_in[16];
    const float* Wp2 = (const float*)d_in[17];
    const float* bp2 = (const float*)d_in[18];
    float* out = (float*)d_out;

    // workspace layout (bf16 buffers padded +128 rows for OOB tile reads, BM=128)
    size_t NP = (size_t)(N_NODES + 128);
    unsigned short* xb  = (unsigned short*)d_ws;          // NP x 512 (reused for UV later)
    unsigned short* h0  = xb + NP * 512;                  // NP x 512
    unsigned short* h1  = h0 + NP * 512;                  // NP x 256
    unsigned short* hr  = h1 + NP * 256;                  // N x 1536 max (fused C)
    unsigned short* Wt0 = hr + (size_t)R_REL * N_NODES * 512;
    unsigned short* Wt1 = Wt0 + 786432;
    unsigned short* Wt2 = Wt1 + 393216;
    unsigned short* Wt3 = Wt2 + 98304;
    unsigned short* But = Wt3 + 32768;                    // 128*64
    float* bsum = (float*)(But + 128 * 64);               // 960 summed biases
    float* sn   = bsum + 960;
    float* dn   = sn + (size_t)R_REL * N_NODES;
    int* outcnt = (int*)(dn + (size_t)R_REL * N_NODES);
    int* incnt  = outcnt + (size_t)R_REL * N_NODES;
    int* ell    = incnt + (size_t)R_REL * N_NODES;        // 3*N*32 ints
    unsigned short* UV = xb;                              // N x 128 (after layers done)
    const unsigned short* Wt[4] = {Wt0, Wt1, Wt2, Wt3};
    const int boff[4] = {0, 512, 768, 896};

    hipMemsetAsync(outcnt, 0, sizeof(int) * 2 * R_REL * N_NODES, stream);
    count_fill_kernel<<<cdiv_h(R_REL * E_EDGES, 256), 256, 0, stream>>>(
        rel_src, rel_dst, outcnt, incnt, ell);

    // one fused aux pass: norms (sn,dn) + x->bf16 + weight transposes + bsum
    aux_kernel<<<cdiv_h(AUX_NORM + AUX_F2B + AUX_PREP, 256), 256, 0, stream>>>(
        outcnt, sn, x, xb,
        W[0], W[1], W[2], W[3], Wp1, bias[0], bias[1], bias[2], bias[3],
        Wt0, Wt1, Wt2, Wt3, But, bsum);

    const int dims[5]  = {512, 512, 256, 128, 64};
    const int ndpad[4] = {1536, 768, 384, 256};   // 3*dout padded to x128
    unsigned short* hbufs[4] = {h0, h1, h0, h1};
    const unsigned short* hcur = xb;
    for (int l = 0; l < 4; ++l) {
        int din = dims[l], dout = dims[l + 1], NdPad = ndpad[l];
        unsigned short* hnext = hbufs[l];
        dim3 grid(NdPad / 128, cdiv_h(N_NODES, 128));
        gemm_bf16_fused<<<grid, 256, 0, stream>>>(hcur, Wt[l], hr, sn, N_NODES, din, NdPad, dout);
        // lgh = log2(dout/16): threads per node = dout/16, each handling 2 chunks
        int lgh = (dout == 512) ? 5 : (dout == 256) ? 4 : (dout == 128) ? 3 : 2;
        int total = N_NODES << lgh;
        gather3_kernel<<<cdiv_h(total, 256), 256, 0, stream>>>(
            hr, NdPad / 8, dout / 8, ell, incnt, dn, bsum + boff[l], hnext, lgh, total,
            (l < 3) ? 1 : 0);
        hcur = hnext;
    }

    // UV = h_final @ [Wp1_top | Wp1_bot]  (M=N, K=64, Nd=128)
    dim3 uvgrid(1, cdiv_h(N_NODES, 128));
    gemm_bf16_fused<<<uvgrid, 256, 0, stream>>>(hcur, But, UV, nullptr, N_NODES, 64, 128, 128);

    edge_score_kernel<<<cdiv_h(2 * EP_EDGES, 256), 256, 0, stream>>>(
        UV, pos_src, pos_dst, neg_src, neg_dst, bp1, Wp2, bp2, out);
}